// Round 5
// baseline (580.151 us; speedup 1.0000x reference)
//
#include <hip/hip_runtime.h>

#define HW_PIX (2160 * 3840)   // 8294400 pixels
#define QPIX   (HW_PIX / 4)    // 2073600 pixel-quads
#define D   33
#define D3  (33 * 33 * 33)     // 35937
#define M   (3 * D3)           // 107811 floats per (half, n) slice
#define MP  107812             // padded accum row stride (16 B-aligned rows)
#define NLUT 350

// Paired-entry grid: idx[h][b][g][r], b,g,r in [0,32). Entry = TWO adjacent
// uint4 (32 B, one 64 B line): uint4 #0 = b-level b, #1 = b-level b+1.
// Each uint4 packs 12 values at 10 bits: word[k]=q[3k]|q[3k+1]<<10|q[3k+2]<<20,
// j = (gg*2+rr)*3+c.
#define PIDX  (32 * 32 * 32)       // 32768 entries per half
#define PU4   (PIDX * 2)           // uint4 count per half

#define CH    1024                 // floats per reduce tile (256 thr x f4)
#define HT    ((M + CH - 1) / CH)  // 106 tiles per (split, half)

typedef float        f4  __attribute__((ext_vector_type(4)));
typedef unsigned int u4  __attribute__((ext_vector_type(4)));
typedef float        f4u __attribute__((ext_vector_type(4), aligned(4)));

// ---------------------------------------------------------------------------
// Kernel A: partial[s][h][tile] = sum over split-s n's of lut slices.
// NS=8 -> 1696 blocks (6.6/CU, 26 waves/CU). Each thread sums ONE f4:
// 1 global_load_dwordx4 per chain-step (1 KB/wave-instr; 4x fewer VMEM
// issues than the scalar version), two independent pointer chains for MLP.
// lut is a 302 MB single-pass stream -> nontemporal (no L2 allocate).
// Slice stride M*4 B = 12 mod 16 -> f4 loads are dword-aligned only; gfx950
// handles unaligned global vectors in HW and all bytes of each line are
// consumed by neighboring lanes, so BW is unaffected.
// ---------------------------------------------------------------------------
template<int NS>
__global__ __launch_bounds__(256) void reduce_kernel(
    const float* __restrict__ lut,    // [2][NLUT][M]
    float* __restrict__ accum)        // [NS][2][MP]
{
    const int bid = blockIdx.x;
    const int s   = bid / (2 * HT);              // n-split 0..NS-1
    const int rm  = bid - s * (2 * HT);
    const int h   = rm / HT;                     // half 0..1
    const int ti  = rm - h * HT;
    const int vb  = ti * CH;

    const int cbase = NLUT / NS, crem = NLUT % NS;
    const int start = s * cbase + min(s, crem);
    const int count = cbase + (s < crem ? 1 : 0);

    const float* __restrict__ base = lut + ((long long)h * NLUT + start) * M;
    float* __restrict__ arow = accum + (long long)(s * 2 + h) * MP;

    if (vb + CH <= M) {
        const int idx = vb + (int)threadIdx.x * 4;
        const int c0  = count >> 1;
        f4 a = {0.f, 0.f, 0.f, 0.f};
        f4 b = {0.f, 0.f, 0.f, 0.f};
        const float* pA = base + idx;
        const float* pB = base + (long long)c0 * M + idx;
        #pragma unroll 2
        for (int n = 0; n < c0; ++n, pA += M, pB += M) {
            a += __builtin_nontemporal_load((const f4u*)pA);
            b += __builtin_nontemporal_load((const f4u*)pB);
        }
        if (count & 1)
            b += __builtin_nontemporal_load((const f4u*)pB);
        a += b;
        *(f4*)(arow + idx) = a;                  // MP rows: 16 B-aligned
    } else {
        // tail tile (291 floats): scalar per-element
        for (int e = vb + (int)threadIdx.x; e < M; e += 256) {
            const float* p = base + e;
            float a = 0.f;
            for (int n = 0; n < count; ++n, p += M)
                a += __builtin_nontemporal_load(p);
            arow[e] = a;
        }
    }
}

// ---------------------------------------------------------------------------
// Kernel B: sum the ns partials, quantize + pack into paired 32 B entries.
// accum is <=6.9 MB -> L2/L3-resident; the extra split reads are cheap.
// ---------------------------------------------------------------------------
__global__ __launch_bounds__(256) void pack_kernel(
    const float* __restrict__ accum,  // [ns][2][MP]
    uint4* __restrict__ packed,       // [2][PIDX][2]
    int ns)
{
    int t = blockIdx.x * 256 + threadIdx.x;
    if (t >= 2 * PIDX) return;
    int h = t >> 15;
    int e = t & (PIDX - 1);
    int b = e >> 10;
    int g = (e >> 5) & 31;
    int r = e & 31;

    const float* A = accum + (long long)h * MP;  // split s at + s*2*MP
    uint4 E[2];
    #pragma unroll
    for (int bb = 0; bb < 2; ++bb) {
        unsigned q[12];
        int j = 0;
        #pragma unroll
        for (int gg = 0; gg < 2; ++gg)
            #pragma unroll
            for (int rr = 0; rr < 2; ++rr)
                #pragma unroll
                for (int c = 0; c < 3; ++c) {
                    int i = c * D3 + ((b + bb) * D + (g + gg)) * D + (r + rr);
                    float v = 0.f;
                    for (int s = 0; s < ns; ++s)
                        v += A[i + (long long)s * 2 * MP];
                    v = fminf(fmaxf(v, 0.0f), 1.0f);
                    q[j++] = (unsigned)(v * 1023.0f + 0.5f);
                }
        E[bb].x = q[0] | (q[1]  << 10) | (q[2]  << 20);
        E[bb].y = q[3] | (q[4]  << 10) | (q[5]  << 20);
        E[bb].z = q[6] | (q[7]  << 10) | (q[8]  << 20);
        E[bb].w = q[9] | (q[10] << 10) | (q[11] << 20);
    }
    packed[2 * t]     = E[0];
    packed[2 * t + 1] = E[1];
}

// ---------------------------------------------------------------------------
// Trilinear apply for 4 independent pixels: all 8 gathers (one 64 B line per
// pixel) issued before any unpack -> 8 loads in flight per dependent stage.
// ---------------------------------------------------------------------------
__device__ __forceinline__ void apply4(const u4* __restrict__ L,
                                       const float* r, const float* g, const float* b,
                                       float* pr, float* pg, float* pb)
{
    u4 E0[4], E1[4];
    float fr[4], fg[4], fb[4];
    #pragma unroll
    for (int i = 0; i < 4; ++i) {
        float xr = r[i] * 32.0f, xg = g[i] * 32.0f, xb = b[i] * 32.0f;
        int r0 = min(max((int)xr, 0), 31);   // inputs >= 0: trunc == floor
        int g0 = min(max((int)xg, 0), 31);
        int b0 = min(max((int)xb, 0), 31);
        fr[i] = xr - (float)r0;
        fg[i] = xg - (float)g0;
        fb[i] = xb - (float)b0;
        int idx = (b0 << 10) + (g0 << 5) + r0;
        E0[i] = L[2 * idx];          // b-level b0
        E1[i] = L[2 * idx + 1];      // b-level b0+1 (same 64 B line)
    }
    const float inv = 1.0f / 1023.0f;
    #pragma unroll
    for (int i = 0; i < 4; ++i) {
        float w00 = (1.0f - fg[i]) * (1.0f - fr[i]);
        float w01 = (1.0f - fg[i]) * fr[i];
        float w10 = fg[i] * (1.0f - fr[i]);
        float w11 = fg[i] * fr[i];
        float wb0 = 1.0f - fb[i], wb1 = fb[i];

        float sr, sg, sb;
        {
            float a00 = wb0 * w00, a01 = wb0 * w01, a10 = wb0 * w10, a11 = wb0 * w11;
            sr = a00 * (float)( E0[i].x        & 1023) + a01 * (float)( E0[i].y        & 1023)
               + a10 * (float)( E0[i].z        & 1023) + a11 * (float)( E0[i].w        & 1023);
            sg = a00 * (float)((E0[i].x >> 10) & 1023) + a01 * (float)((E0[i].y >> 10) & 1023)
               + a10 * (float)((E0[i].z >> 10) & 1023) + a11 * (float)((E0[i].w >> 10) & 1023);
            sb = a00 * (float)((E0[i].x >> 20) & 1023) + a01 * (float)((E0[i].y >> 20) & 1023)
               + a10 * (float)((E0[i].z >> 20) & 1023) + a11 * (float)((E0[i].w >> 20) & 1023);
        }
        {
            float a00 = wb1 * w00, a01 = wb1 * w01, a10 = wb1 * w10, a11 = wb1 * w11;
            sr += a00 * (float)( E1[i].x        & 1023) + a01 * (float)( E1[i].y        & 1023)
                + a10 * (float)( E1[i].z        & 1023) + a11 * (float)( E1[i].w        & 1023);
            sg += a00 * (float)((E1[i].x >> 10) & 1023) + a01 * (float)((E1[i].y >> 10) & 1023)
                + a10 * (float)((E1[i].z >> 10) & 1023) + a11 * (float)((E1[i].w >> 10) & 1023);
            sb += a00 * (float)((E1[i].x >> 20) & 1023) + a01 * (float)((E1[i].y >> 20) & 1023)
                + a10 * (float)((E1[i].z >> 20) & 1023) + a11 * (float)((E1[i].w >> 20) & 1023);
        }
        pr[i] = sr * inv; pg[i] = sg * inv; pb[i] = sb * inv;
    }
}

// ---------------------------------------------------------------------------
// Kernel C: fused  I_f = apply(CL1, apply(CL0, gt)) — 2 line-touches/pixel.
// 4 pixels/thread via float4 non-temporal stream I/O (keeps the 2 MB LUT
// L2-resident against the 199 MB gt/out stream) + ILP-4 gather chains.
// ---------------------------------------------------------------------------
__global__ __launch_bounds__(256) void fused_apply_kernel(
    const float* __restrict__ gt,       // [3][H][W]
    const u4* __restrict__ packed,      // [2][PIDX][2]
    float* __restrict__ out)            // [3][H][W]
{
    int q = blockIdx.x * 256 + threadIdx.x;
    if (q >= QPIX) return;

    const f4* g4 = (const f4*)gt;
    f4 Rv = __builtin_nontemporal_load(g4 + q);
    f4 Gv = __builtin_nontemporal_load(g4 + q + QPIX);
    f4 Bv = __builtin_nontemporal_load(g4 + q + 2 * QPIX);

    float r0[4] = {Rv.x, Rv.y, Rv.z, Rv.w};
    float g0[4] = {Gv.x, Gv.y, Gv.z, Gv.w};
    float b0[4] = {Bv.x, Bv.y, Bv.z, Bv.w};
    float r1[4], g1[4], b1[4], r2[4], g2[4], b2[4];

    apply4(packed,       r0, g0, b0, r1, g1, b1);
    apply4(packed + PU4, r1, g1, b1, r2, g2, b2);

    f4 Ro = {r2[0], r2[1], r2[2], r2[3]};
    f4 Go = {g2[0], g2[1], g2[2], g2[3]};
    f4 Bo = {b2[0], b2[1], b2[2], b2[3]};
    f4* o4 = (f4*)out;
    __builtin_nontemporal_store(Ro, o4 + q);
    __builtin_nontemporal_store(Go, o4 + q + QPIX);
    __builtin_nontemporal_store(Bo, o4 + q + 2 * QPIX);
}

extern "C" void kernel_launch(void* const* d_in, const int* in_sizes, int n_in,
                              void* d_out, int out_size, void* d_ws, size_t ws_size,
                              hipStream_t stream)
{
    const float* gt  = (const float*)d_in[0];
    const float* lut = (const float*)d_in[1];
    // d_in[2] / d_in[3] (L0, L1) are dead code in the reference.
    float* out = (float*)d_out;

    const size_t packed_bytes = (size_t)2 * PU4 * sizeof(uint4);           // 2 MiB
    const size_t a8 = (((size_t)8 * 2 * MP * sizeof(float)) + 31) & ~(size_t)31; // 6,899,968
    const size_t a1 = (((size_t)1 * 2 * MP * sizeof(float)) + 31) & ~(size_t)31; //   862,496

    int ns; size_t poff;
    if (ws_size >= a8 + packed_bytes) { ns = 8; poff = a8; }
    else                              { ns = 1; poff = a1; }   // safe fallback

    float* accum  = (float*)d_ws;
    u4*    packed = (u4*)((char*)d_ws + poff);

    if (ns == 8)
        reduce_kernel<8><<<dim3(8 * 2 * HT), dim3(256), 0, stream>>>(lut, accum);
    else
        reduce_kernel<1><<<dim3(1 * 2 * HT), dim3(256), 0, stream>>>(lut, accum);

    pack_kernel<<<dim3((2 * PIDX + 255) / 256), dim3(256), 0, stream>>>(
        accum, (uint4*)packed, ns);
    fused_apply_kernel<<<dim3((QPIX + 255) / 256), dim3(256), 0, stream>>>(gt, packed, out);
}

// Round 6
// 533.336 us; speedup vs baseline: 1.0878x; 1.0878x over previous
//
#include <hip/hip_runtime.h>

#define HW_PIX (2160 * 3840)   // 8294400 pixels
#define QPIX   (HW_PIX / 4)    // 2073600 pixel-quads
#define D   33
#define D3  (33 * 33 * 33)     // 35937
#define M   (3 * D3)           // 107811 floats per (half, n) slice
#define NLUT 350
#define TWO_M (2 * M)          // 215622

// Paired-entry grid: idx[h][b][g][r], b,g,r in [0,32). Entry = TWO adjacent
// uint4 (32 B, one 64 B line): uint4 #0 = b-level b, #1 = b-level b+1.
// Each uint4 packs 12 values at 10 bits: word[k]=q[3k]|q[3k+1]<<10|q[3k+2]<<20,
// j = (gg*2+rr)*3+c.
#define PIDX  (32 * 32 * 32)       // 32768 entries per half
#define PU4   (PIDX * 2)           // uint4 count per half

#define HB     422                 // ceil(M/256) 256-output blocks per half

typedef float        f4 __attribute__((ext_vector_type(4)));
typedef unsigned int u4 __attribute__((ext_vector_type(4)));

// ---------------------------------------------------------------------------
// Kernel A: partial[s][h][v] = sum over n in split s of lut[h][n][v].
// NS=2: grid = 1688 blocks (6.6/CU, ~26 waves/CU). Wave w owns a 43/44-long
// n-chunk, split into TWO independent pointer chains x 4 offset streams =
// 8 independent accumulators -> up to 32 loads in flight per wave.
// lut is a 302 MB single-pass stream -> nontemporal (no L2 allocate).
// NOTE (round 5): do NOT vectorize these loads to dwordx4 — slice stride
// M*4 B = 12 mod 16, so f4 loads are misaligned, split at 64 B lines, and
// regress 534 -> 580 us. Scalar dword loads here are the proven optimum.
// ---------------------------------------------------------------------------
template<int NS>
__global__ __launch_bounds__(256) void reduce_kernel(
    const float* __restrict__ lut,    // [2][NLUT][M]
    float* __restrict__ accum)        // [NS][2][M]
{
    const int lane = threadIdx.x & 63;
    const int w    = threadIdx.x >> 6;           // 0..3
    const int bid  = blockIdx.x;
    const int s    = bid / (2 * HB);             // n-split 0..NS-1
    const int rem  = bid - s * (2 * HB);
    const int h    = rem / HB;                   // half 0..1
    const int vb   = (rem - h * HB) * 256;       // within-half output base

    const int C = NLUT / NS;                     // 175 (NS=2) or 350
    const int q = C >> 2, r = C & 3;
    const int start = s * C + w * q + min(w, r);
    const int count = q + (w < r ? 1 : 0);       // 43..44 (NS=2)

    const float* __restrict__ hb =
        lut + ((long long)h * NLUT + start) * M; // wave-uniform

    int off[4];
    #pragma unroll
    for (int k = 0; k < 4; ++k) {
        int v = vb + lane + 64 * k;
        off[k] = (v < M) ? v : 0;                // clamp OOB lanes (store-masked)
    }

    // Two independent n-chains (cA over [0,c0), cB over [c0,count))
    const int c0 = count >> 1;
    float a0 = 0.f, a1 = 0.f, a2 = 0.f, a3 = 0.f;
    float b0 = 0.f, b1 = 0.f, b2 = 0.f, b3 = 0.f;
    {
        const float* pA = hb;
        const float* pB = hb + (long long)c0 * M;
        const int cB = count - c0;
        int n = 0;
        #pragma unroll 2
        for (; n < c0; ++n, pA += M, pB += M) {
            a0 += __builtin_nontemporal_load(pA + off[0]);
            a1 += __builtin_nontemporal_load(pA + off[1]);
            a2 += __builtin_nontemporal_load(pA + off[2]);
            a3 += __builtin_nontemporal_load(pA + off[3]);
            b0 += __builtin_nontemporal_load(pB + off[0]);
            b1 += __builtin_nontemporal_load(pB + off[1]);
            b2 += __builtin_nontemporal_load(pB + off[2]);
            b3 += __builtin_nontemporal_load(pB + off[3]);
        }
        if (cB > c0) {                           // odd count: one extra on B
            b0 += __builtin_nontemporal_load(pB + off[0]);
            b1 += __builtin_nontemporal_load(pB + off[1]);
            b2 += __builtin_nontemporal_load(pB + off[2]);
            b3 += __builtin_nontemporal_load(pB + off[3]);
        }
    }
    const float s0 = a0 + b0, s1 = a1 + b1, s2 = a2 + b2, s3 = a3 + b3;

    __shared__ float red[4][64][4];
    red[w][lane][0] = s0;
    red[w][lane][1] = s1;
    red[w][lane][2] = s2;
    red[w][lane][3] = s3;
    __syncthreads();

    const int o = threadIdx.x;
    const int v = vb + o;                        // o = 64*k + ln matches slot
    if (v < M) {
        int ln = o & 63, k = o >> 6;
        float t = (red[0][ln][k] + red[1][ln][k])
                + (red[2][ln][k] + red[3][ln][k]);
        accum[((long long)(s * 2 + h)) * M + v] = t;
    }
}

// ---------------------------------------------------------------------------
// Kernel B: sum the ns partials, quantize + pack into paired 32 B entries.
// ---------------------------------------------------------------------------
__global__ __launch_bounds__(256) void pack_kernel(
    const float* __restrict__ accum,  // [ns][2][M]
    uint4* __restrict__ packed,       // [2][PIDX][2]
    int ns)
{
    int t = blockIdx.x * 256 + threadIdx.x;
    if (t >= 2 * PIDX) return;
    int h = t >> 15;
    int e = t & (PIDX - 1);
    int b = e >> 10;
    int g = (e >> 5) & 31;
    int r = e & 31;

    const float* A = accum + (long long)h * M;   // split s at +s*TWO_M
    uint4 E[2];
    #pragma unroll
    for (int bb = 0; bb < 2; ++bb) {
        unsigned q[12];
        int j = 0;
        #pragma unroll
        for (int gg = 0; gg < 2; ++gg)
            #pragma unroll
            for (int rr = 0; rr < 2; ++rr)
                #pragma unroll
                for (int c = 0; c < 3; ++c) {
                    int i = c * D3 + ((b + bb) * D + (g + gg)) * D + (r + rr);
                    float v = A[i];
                    for (int s = 1; s < ns; ++s) v += A[i + (long long)s * TWO_M];
                    v = fminf(fmaxf(v, 0.0f), 1.0f);
                    q[j++] = (unsigned)(v * 1023.0f + 0.5f);
                }
        E[bb].x = q[0] | (q[1]  << 10) | (q[2]  << 20);
        E[bb].y = q[3] | (q[4]  << 10) | (q[5]  << 20);
        E[bb].z = q[6] | (q[7]  << 10) | (q[8]  << 20);
        E[bb].w = q[9] | (q[10] << 10) | (q[11] << 20);
    }
    packed[2 * t]     = E[0];
    packed[2 * t + 1] = E[1];
}

// ---------------------------------------------------------------------------
// Trilinear apply for 4 independent pixels: all 8 gathers (one 64 B line per
// pixel) issued before any unpack -> 8 loads in flight per dependent stage.
// ---------------------------------------------------------------------------
__device__ __forceinline__ void apply4(const u4* __restrict__ L,
                                       const float* r, const float* g, const float* b,
                                       float* pr, float* pg, float* pb)
{
    u4 E0[4], E1[4];
    float fr[4], fg[4], fb[4];
    #pragma unroll
    for (int i = 0; i < 4; ++i) {
        float xr = r[i] * 32.0f, xg = g[i] * 32.0f, xb = b[i] * 32.0f;
        int r0 = min(max((int)xr, 0), 31);   // inputs >= 0: trunc == floor
        int g0 = min(max((int)xg, 0), 31);
        int b0 = min(max((int)xb, 0), 31);
        fr[i] = xr - (float)r0;
        fg[i] = xg - (float)g0;
        fb[i] = xb - (float)b0;
        int idx = (b0 << 10) + (g0 << 5) + r0;
        E0[i] = L[2 * idx];          // b-level b0
        E1[i] = L[2 * idx + 1];      // b-level b0+1 (same 64 B line)
    }
    const float inv = 1.0f / 1023.0f;
    #pragma unroll
    for (int i = 0; i < 4; ++i) {
        float w00 = (1.0f - fg[i]) * (1.0f - fr[i]);
        float w01 = (1.0f - fg[i]) * fr[i];
        float w10 = fg[i] * (1.0f - fr[i]);
        float w11 = fg[i] * fr[i];
        float wb0 = 1.0f - fb[i], wb1 = fb[i];

        float sr, sg, sb;
        {
            float a00 = wb0 * w00, a01 = wb0 * w01, a10 = wb0 * w10, a11 = wb0 * w11;
            sr = a00 * (float)( E0[i].x        & 1023) + a01 * (float)( E0[i].y        & 1023)
               + a10 * (float)( E0[i].z        & 1023) + a11 * (float)( E0[i].w        & 1023);
            sg = a00 * (float)((E0[i].x >> 10) & 1023) + a01 * (float)((E0[i].y >> 10) & 1023)
               + a10 * (float)((E0[i].z >> 10) & 1023) + a11 * (float)((E0[i].w >> 10) & 1023);
            sb = a00 * (float)((E0[i].x >> 20) & 1023) + a01 * (float)((E0[i].y >> 20) & 1023)
               + a10 * (float)((E0[i].z >> 20) & 1023) + a11 * (float)((E0[i].w >> 20) & 1023);
        }
        {
            float a00 = wb1 * w00, a01 = wb1 * w01, a10 = wb1 * w10, a11 = wb1 * w11;
            sr += a00 * (float)( E1[i].x        & 1023) + a01 * (float)( E1[i].y        & 1023)
                + a10 * (float)( E1[i].z        & 1023) + a11 * (float)( E1[i].w        & 1023);
            sg += a00 * (float)((E1[i].x >> 10) & 1023) + a01 * (float)((E1[i].y >> 10) & 1023)
                + a10 * (float)((E1[i].z >> 10) & 1023) + a11 * (float)((E1[i].w >> 10) & 1023);
            sb += a00 * (float)((E1[i].x >> 20) & 1023) + a01 * (float)((E1[i].y >> 20) & 1023)
                + a10 * (float)((E1[i].z >> 20) & 1023) + a11 * (float)((E1[i].w >> 20) & 1023);
        }
        pr[i] = sr * inv; pg[i] = sg * inv; pb[i] = sb * inv;
    }
}

// ---------------------------------------------------------------------------
// Kernel C: fused  I_f = apply(CL1, apply(CL0, gt)) — 2 line-touches/pixel.
// 4 pixels/thread via float4 non-temporal stream I/O (keeps the 2 MB LUT
// L2-resident against the 199 MB gt/out stream) + ILP-4 gather chains.
// ---------------------------------------------------------------------------
__global__ __launch_bounds__(256) void fused_apply_kernel(
    const float* __restrict__ gt,       // [3][H][W]
    const u4* __restrict__ packed,      // [2][PIDX][2]
    float* __restrict__ out)            // [3][H][W]
{
    int q = blockIdx.x * 256 + threadIdx.x;
    if (q >= QPIX) return;

    const f4* g4 = (const f4*)gt;
    f4 Rv = __builtin_nontemporal_load(g4 + q);
    f4 Gv = __builtin_nontemporal_load(g4 + q + QPIX);
    f4 Bv = __builtin_nontemporal_load(g4 + q + 2 * QPIX);

    float r0[4] = {Rv.x, Rv.y, Rv.z, Rv.w};
    float g0[4] = {Gv.x, Gv.y, Gv.z, Gv.w};
    float b0[4] = {Bv.x, Bv.y, Bv.z, Bv.w};
    float r1[4], g1[4], b1[4], r2[4], g2[4], b2[4];

    apply4(packed,       r0, g0, b0, r1, g1, b1);
    apply4(packed + PU4, r1, g1, b1, r2, g2, b2);

    f4 Ro = {r2[0], r2[1], r2[2], r2[3]};
    f4 Go = {g2[0], g2[1], g2[2], g2[3]};
    f4 Bo = {b2[0], b2[1], b2[2], b2[3]};
    f4* o4 = (f4*)out;
    __builtin_nontemporal_store(Ro, o4 + q);
    __builtin_nontemporal_store(Go, o4 + q + QPIX);
    __builtin_nontemporal_store(Bo, o4 + q + 2 * QPIX);
}

extern "C" void kernel_launch(void* const* d_in, const int* in_sizes, int n_in,
                              void* d_out, int out_size, void* d_ws, size_t ws_size,
                              hipStream_t stream)
{
    const float* gt  = (const float*)d_in[0];
    const float* lut = (const float*)d_in[1];
    // d_in[2] / d_in[3] (L0, L1) are dead code in the reference.
    float* out = (float*)d_out;

    const size_t packed_bytes = (size_t)2 * PU4 * sizeof(uint4);            // 2 MiB
    size_t a2 = ((size_t)2 * TWO_M * sizeof(float) + 31) & ~(size_t)31;     // 1,724,992
    size_t a1 = ((size_t)1 * TWO_M * sizeof(float) + 31) & ~(size_t)31;     //   862,496
    int ns; size_t poff;
    if (ws_size >= a2 + packed_bytes) { ns = 2; poff = a2; }
    else                              { ns = 1; poff = a1; }

    float* accum  = (float*)d_ws;
    u4*    packed = (u4*)((char*)d_ws + poff);

    if (ns == 2)
        reduce_kernel<2><<<dim3(2 * 2 * HB), dim3(256), 0, stream>>>(lut, accum);
    else
        reduce_kernel<1><<<dim3(1 * 2 * HB), dim3(256), 0, stream>>>(lut, accum);

    pack_kernel<<<dim3((2 * PIDX + 255) / 256), dim3(256), 0, stream>>>(
        accum, (uint4*)packed, ns);
    fused_apply_kernel<<<dim3((QPIX + 255) / 256), dim3(256), 0, stream>>>(gt, packed, out);
}